// Round 6
// baseline (169.337 us; speedup 1.0000x reference)
//
#include <hip/hip_runtime.h>

#define DIM 4096
#define K_SEL 204            // int(4096 * (1.0 - 0.95)) == 204
#define CAP 256              // interval candidates: mean 165, sd 12.6 (7 sigma)
#define WPB 4                // 4 independent rows per block (one per wave, NO barriers)
#define LOF 1.4375f          // P(cnt(>LOF) < K)  ~ 6 sigma safe (fixed dataset, verified R2-R5)
#define HIF 1.8125f          // P(cnt(>HIF) >= K) ~ 5 sigma safe
#define KLO 0x3FB80000u      // bits of 1.4375
#define KHI 0x3FE80000u      // bits of 1.8125

typedef float nfloat4 __attribute__((ext_vector_type(4)));   // native vec for nt-store

// Monotonic key for the (never-taken) exact fallback: handles any floats.
__device__ __forceinline__ unsigned int fkey(float f) {
    unsigned int u = __float_as_uint(f);
    return (u & 0x80000000u) ? ~u : (u | 0x80000000u);
}
__device__ __forceinline__ float finv(unsigned int k) {
    unsigned int u = (k & 0x80000000u) ? (k ^ 0x80000000u) : ~k;
    return __uint_as_float(u);
}
// popcount of mask bits strictly below this lane (v_mbcnt_lo + v_mbcnt_hi)
__device__ __forceinline__ unsigned int prefcount(unsigned long long m) {
    return __builtin_amdgcn_mbcnt_hi((unsigned int)(m >> 32),
           __builtin_amdgcn_mbcnt_lo((unsigned int)m, 0u));
}
// nontemporal float4 store: keep the 256MB output stream OUT of L3 so the
// (exactly L3-sized) input stays Infinity-Cache-resident across graph replays.
// (R5 counters: FETCH dropped to ~half the input = L3 equilibrium. Keep.)
__device__ __forceinline__ void nt_store4(float4* p, float4 w) {
    nfloat4 nv;
    nv.x = w.x; nv.y = w.y; nv.z = w.z; nv.w = w.w;
    __builtin_nontemporal_store(nv, (nfloat4*)p);
}

// 256 threads = 4 waves, each wave owns one ROW. Zero __syncthreads.
__global__ __launch_bounds__(256, 8) void sparsify_topk(
        const float* __restrict__ x, float* __restrict__ out) {
    __shared__ float wc_all[WPB][CAP];        // 4 KB, partitioned per wave

    const int wave = threadIdx.x >> 6;
    const int lane = threadIdx.x & 63;
    float* wc = wc_all[wave];
    const size_t base = (size_t)(blockIdx.x * WPB + wave) * DIM;

    // ---- load row: 16 x float4 per lane, 64 VGPRs, coalesced 1KB/instr ----
    const float4* xv = (const float4*)(x + base);
    float4 v[16];
    #pragma unroll
    for (int c = 0; c < 16; ++c) v[c] = xv[lane + 64 * c];

    // ---- fused count + compact of interval candidates (LOF, HIF] ----
    // positive-float trick: f in (LOF,HIF]  <=>  (bits(f) - KLO - 1) < (KHI - KLO)
    // negatives/NaN have bits >= 0x8000..., which fails the unsigned range test.
    unsigned int cU = 0, ccnt = 0;
    #pragma unroll
    for (int c = 0; c < 16; ++c) {
        float fv[4] = {v[c].x, v[c].y, v[c].z, v[c].w};
        #pragma unroll
        for (int j = 0; j < 4; ++j) {
            float f = fv[j];
            unsigned int u = __float_as_uint(f);
            bool inR = (u - (KLO + 1u)) < (KHI - KLO);   // candidate
            bool pU  = f > HIF;
            unsigned long long mC = __ballot(inR);
            unsigned long long mU = __ballot(pU);
            unsigned int pos = ccnt + prefcount(mC);
            if (inR && (pos < CAP)) wc[pos] = f;         // exec-masked store
            cU   += (unsigned)__popcll(mU);
            ccnt += (unsigned)__popcll(mC);
        }
    }

    const bool fast = (cU < K_SEL) && (cU + ccnt >= K_SEL) && (ccnt <= CAP);
    float thrf;
    unsigned int gt, eqc;

    if (fast) {
        // wave-private LDS readback (compiler inserts lgkmcnt; no barrier)
        float c0 = (lane       < (int)ccnt) ? wc[lane      ] : 0.0f;
        float c1 = (lane + 64  < (int)ccnt) ? wc[lane +  64] : 0.0f;
        float c2 = (lane + 128 < (int)ccnt) ? wc[lane + 128] : 0.0f;
        float c3 = (lane + 192 < (int)ccnt) ? wc[lane + 192] : 0.0f;
        // binary search on positive-float bit patterns in (KLO, KHI]
        unsigned int lo = KLO, hi = KHI;
        unsigned int c_lo = cU + ccnt, c_hi = cU;      // cnt_gt at both ends
        while (hi - lo > 1) {
            unsigned int mid = lo + ((hi - lo) >> 1);
            float midf = __uint_as_float(mid);
            unsigned int cm = cU
                + (unsigned)__popcll(__ballot(c0 > midf))
                + (unsigned)__popcll(__ballot(c1 > midf))
                + (unsigned)__popcll(__ballot(c2 > midf))
                + (unsigned)__popcll(__ballot(c3 > midf));
            if (cm >= K_SEL) { lo = mid; c_lo = cm; }
            else             { hi = mid; c_hi = cm; }
        }
        thrf = __uint_as_float(hi);    // k-th largest value
        gt = c_hi;                     // strictly greater
        eqc = c_lo - c_hi;             // equal (adjacent bit patterns -> exact)
    } else {
        // ---- exact fallback: 32-step search in monotonic-key domain ----
        unsigned int c_lo = 0;
        #pragma unroll
        for (int c = 0; c < 16; ++c) {
            c_lo += (unsigned)__popcll(__ballot(fkey(v[c].x) > 0u));
            c_lo += (unsigned)__popcll(__ballot(fkey(v[c].y) > 0u));
            c_lo += (unsigned)__popcll(__ballot(fkey(v[c].z) > 0u));
            c_lo += (unsigned)__popcll(__ballot(fkey(v[c].w) > 0u));
        }
        unsigned int lo = 0u, hi = 0xFFFFFFFFu, c_hi = 0;
        while (hi - lo > 1) {
            unsigned int mid = lo + ((hi - lo) >> 1);
            unsigned int cm = 0;
            #pragma unroll
            for (int c = 0; c < 16; ++c) {
                cm += (unsigned)__popcll(__ballot(fkey(v[c].x) > mid));
                cm += (unsigned)__popcll(__ballot(fkey(v[c].y) > mid));
                cm += (unsigned)__popcll(__ballot(fkey(v[c].z) > mid));
                cm += (unsigned)__popcll(__ballot(fkey(v[c].w) > mid));
            }
            if (cm >= K_SEL) { lo = mid; c_lo = cm; }
            else             { hi = mid; c_hi = cm; }
        }
        thrf = finv(hi);
        gt = c_hi;
        eqc = c_lo - c_hi;
    }

    const unsigned int need = K_SEL - gt;     // >= 1 by search invariant
    float4* ov = (float4*)(out + base);

    if (eqc == need) {
        // common case: keep everything >= thr (exactly K survive)
        #pragma unroll
        for (int c = 0; c < 16; ++c) {
            float4 w = v[c];
            w.x = (w.x >= thrf) ? w.x : 0.0f;
            w.y = (w.y >= thrf) ? w.y : 0.0f;
            w.z = (w.z >= thrf) ? w.z : 0.0f;
            w.w = (w.w >= thrf) ? w.w : 0.0f;
            nt_store4(&ov[lane + 64 * c], w);
        }
    } else {
        // rare tie path: keep first `need` equals in global index order
        // element index = 256*c + 4*lane + j  -> order (c, lane, j)
        unsigned int base_c = 0;
        #pragma unroll
        for (int c = 0; c < 16; ++c) {
            unsigned long long m0 = __ballot(v[c].x == thrf);
            unsigned long long m1 = __ballot(v[c].y == thrf);
            unsigned long long m2 = __ballot(v[c].z == thrf);
            unsigned long long m3 = __ballot(v[c].w == thrf);
            unsigned int pl = prefcount(m0) + prefcount(m1)
                            + prefcount(m2) + prefcount(m3);
            unsigned int b0 = (unsigned)((m0 >> lane) & 1ull);
            unsigned int b1 = (unsigned)((m1 >> lane) & 1ull);
            unsigned int b2 = (unsigned)((m2 >> lane) & 1ull);
            unsigned int r0 = base_c + pl;
            unsigned int r1 = r0 + b0;
            unsigned int r2 = r1 + b1;
            unsigned int r3 = r2 + b2;
            float4 w = v[c];
            w.x = (w.x > thrf || (w.x == thrf && r0 < need)) ? w.x : 0.0f;
            w.y = (w.y > thrf || (w.y == thrf && r1 < need)) ? w.y : 0.0f;
            w.z = (w.z > thrf || (w.z == thrf && r2 < need)) ? w.z : 0.0f;
            w.w = (w.w > thrf || (w.w == thrf && r3 < need)) ? w.w : 0.0f;
            nt_store4(&ov[lane + 64 * c], w);
            base_c += (unsigned)__popcll(m0) + (unsigned)__popcll(m1)
                    + (unsigned)__popcll(m2) + (unsigned)__popcll(m3);
        }
    }
}

extern "C" void kernel_launch(void* const* d_in, const int* in_sizes, int n_in,
                              void* d_out, int out_size, void* d_ws, size_t ws_size,
                              hipStream_t stream) {
    const float* x = (const float*)d_in[0];
    float* out = (float*)d_out;
    int rows = in_sizes[0] / DIM;             // 16384
    sparsify_topk<<<rows / WPB, 256, 0, stream>>>(x, out);
}

// Round 7
// 82.371 us; speedup vs baseline: 2.0558x; 2.0558x over previous
//
#include <hip/hip_runtime.h>

#define DIM 4096
#define K_SEL 204            // int(4096 * (1.0 - 0.95)) == 204
#define CAP 256              // interval candidates: mean 165, sd 12.6 (7 sigma)
#define WPB 4                // 4 independent rows per block (one per wave, NO barriers)
#define LOF 1.4375f          // P(cnt(>LOF) < K)  ~ 6 sigma safe (fixed dataset, verified R2-R5)
#define HIF 1.8125f          // P(cnt(>HIF) >= K) ~ 5 sigma safe
#define KLO 0x3FB80000u      // bits of 1.4375
#define KHI 0x3FE80000u      // bits of 1.8125

typedef float nfloat4 __attribute__((ext_vector_type(4)));   // native vec for nt-store

// Monotonic key for the (never-taken) exact fallback: handles any floats.
__device__ __forceinline__ unsigned int fkey(float f) {
    unsigned int u = __float_as_uint(f);
    return (u & 0x80000000u) ? ~u : (u | 0x80000000u);
}
__device__ __forceinline__ float finv(unsigned int k) {
    unsigned int u = (k & 0x80000000u) ? (k ^ 0x80000000u) : ~k;
    return __uint_as_float(u);
}
// popcount of mask bits strictly below this lane (v_mbcnt_lo + v_mbcnt_hi)
__device__ __forceinline__ unsigned int prefcount(unsigned long long m) {
    return __builtin_amdgcn_mbcnt_hi((unsigned int)(m >> 32),
           __builtin_amdgcn_mbcnt_lo((unsigned int)m, 0u));
}
// nontemporal float4 store: keep the 256MB output stream OUT of L3 so the
// (exactly L3-sized) input stays Infinity-Cache-resident across graph replays.
// (R5 counters: FETCH dropped to ~half the input = L3 equilibrium. Keep.)
__device__ __forceinline__ void nt_store4(float4* p, float4 w) {
    nfloat4 nv;
    nv.x = w.x; nv.y = w.y; nv.z = w.z; nv.w = w.w;
    __builtin_nontemporal_store(nv, (nfloat4*)p);
}

// 256 threads = 4 waves, each wave owns one ROW. Zero __syncthreads.
// launch_bounds (256, 4): 128-VGPR cap -- room for the 64-reg row + working set
// (R6's (256,8) forced a 32-VGPR fit -> scratch spills -> 2x regression).
__global__ __launch_bounds__(256, 4) void sparsify_topk(
        const float* __restrict__ x, float* __restrict__ out) {
    __shared__ float wc_all[WPB][CAP];        // 4 KB, partitioned per wave

    const int wave = threadIdx.x >> 6;
    const int lane = threadIdx.x & 63;
    float* wc = wc_all[wave];
    const size_t base = (size_t)(blockIdx.x * WPB + wave) * DIM;

    // ---- load row: 16 x float4 per lane, 64 VGPRs, coalesced 1KB/instr ----
    const float4* xv = (const float4*)(x + base);
    float4 v[16];
    #pragma unroll
    for (int c = 0; c < 16; ++c) v[c] = xv[lane + 64 * c];

    // ---- fused count + compact of interval candidates (LOF, HIF] ----
    // positive-float trick: f in (LOF,HIF]  <=>  (bits(f) - KLO - 1) < (KHI - KLO)
    // negatives/NaN have bits >= 0x8000..., which fails the unsigned range test.
    unsigned int cU = 0, ccnt = 0;
    #pragma unroll
    for (int c = 0; c < 16; ++c) {
        float fv[4] = {v[c].x, v[c].y, v[c].z, v[c].w};
        #pragma unroll
        for (int j = 0; j < 4; ++j) {
            float f = fv[j];
            unsigned int u = __float_as_uint(f);
            bool inR = (u - (KLO + 1u)) < (KHI - KLO);   // candidate
            bool pU  = f > HIF;
            unsigned long long mC = __ballot(inR);
            unsigned long long mU = __ballot(pU);
            unsigned int pos = ccnt + prefcount(mC);
            if (inR && (pos < CAP)) wc[pos] = f;         // exec-masked store
            cU   += (unsigned)__popcll(mU);
            ccnt += (unsigned)__popcll(mC);
        }
    }

    const bool fast = (cU < K_SEL) && (cU + ccnt >= K_SEL) && (ccnt <= CAP);
    float thrf;
    unsigned int gt, eqc;

    if (fast) {
        // wave-private LDS readback (compiler inserts lgkmcnt; no barrier)
        float c0 = (lane       < (int)ccnt) ? wc[lane      ] : 0.0f;
        float c1 = (lane + 64  < (int)ccnt) ? wc[lane +  64] : 0.0f;
        float c2 = (lane + 128 < (int)ccnt) ? wc[lane + 128] : 0.0f;
        float c3 = (lane + 192 < (int)ccnt) ? wc[lane + 192] : 0.0f;
        // binary search on positive-float bit patterns in (KLO, KHI]
        unsigned int lo = KLO, hi = KHI;
        unsigned int c_lo = cU + ccnt, c_hi = cU;      // cnt_gt at both ends
        while (hi - lo > 1) {
            unsigned int mid = lo + ((hi - lo) >> 1);
            float midf = __uint_as_float(mid);
            unsigned int cm = cU
                + (unsigned)__popcll(__ballot(c0 > midf))
                + (unsigned)__popcll(__ballot(c1 > midf))
                + (unsigned)__popcll(__ballot(c2 > midf))
                + (unsigned)__popcll(__ballot(c3 > midf));
            if (cm >= K_SEL) { lo = mid; c_lo = cm; }
            else             { hi = mid; c_hi = cm; }
        }
        thrf = __uint_as_float(hi);    // k-th largest value
        gt = c_hi;                     // strictly greater
        eqc = c_lo - c_hi;             // equal (adjacent bit patterns -> exact)
    } else {
        // ---- exact fallback: 32-step search in monotonic-key domain ----
        unsigned int c_lo = 0;
        #pragma unroll
        for (int c = 0; c < 16; ++c) {
            c_lo += (unsigned)__popcll(__ballot(fkey(v[c].x) > 0u));
            c_lo += (unsigned)__popcll(__ballot(fkey(v[c].y) > 0u));
            c_lo += (unsigned)__popcll(__ballot(fkey(v[c].z) > 0u));
            c_lo += (unsigned)__popcll(__ballot(fkey(v[c].w) > 0u));
        }
        unsigned int lo = 0u, hi = 0xFFFFFFFFu, c_hi = 0;
        while (hi - lo > 1) {
            unsigned int mid = lo + ((hi - lo) >> 1);
            unsigned int cm = 0;
            #pragma unroll
            for (int c = 0; c < 16; ++c) {
                cm += (unsigned)__popcll(__ballot(fkey(v[c].x) > mid));
                cm += (unsigned)__popcll(__ballot(fkey(v[c].y) > mid));
                cm += (unsigned)__popcll(__ballot(fkey(v[c].z) > mid));
                cm += (unsigned)__popcll(__ballot(fkey(v[c].w) > mid));
            }
            if (cm >= K_SEL) { lo = mid; c_lo = cm; }
            else             { hi = mid; c_hi = cm; }
        }
        thrf = finv(hi);
        gt = c_hi;
        eqc = c_lo - c_hi;
    }

    const unsigned int need = K_SEL - gt;     // >= 1 by search invariant
    float4* ov = (float4*)(out + base);

    if (eqc == need) {
        // common case: keep everything >= thr (exactly K survive)
        #pragma unroll
        for (int c = 0; c < 16; ++c) {
            float4 w = v[c];
            w.x = (w.x >= thrf) ? w.x : 0.0f;
            w.y = (w.y >= thrf) ? w.y : 0.0f;
            w.z = (w.z >= thrf) ? w.z : 0.0f;
            w.w = (w.w >= thrf) ? w.w : 0.0f;
            nt_store4(&ov[lane + 64 * c], w);
        }
    } else {
        // rare tie path: keep first `need` equals in global index order
        // element index = 256*c + 4*lane + j  -> order (c, lane, j)
        unsigned int base_c = 0;
        #pragma unroll
        for (int c = 0; c < 16; ++c) {
            unsigned long long m0 = __ballot(v[c].x == thrf);
            unsigned long long m1 = __ballot(v[c].y == thrf);
            unsigned long long m2 = __ballot(v[c].z == thrf);
            unsigned long long m3 = __ballot(v[c].w == thrf);
            unsigned int pl = prefcount(m0) + prefcount(m1)
                            + prefcount(m2) + prefcount(m3);
            unsigned int b0 = (unsigned)((m0 >> lane) & 1ull);
            unsigned int b1 = (unsigned)((m1 >> lane) & 1ull);
            unsigned int b2 = (unsigned)((m2 >> lane) & 1ull);
            unsigned int r0 = base_c + pl;
            unsigned int r1 = r0 + b0;
            unsigned int r2 = r1 + b1;
            unsigned int r3 = r2 + b2;
            float4 w = v[c];
            w.x = (w.x > thrf || (w.x == thrf && r0 < need)) ? w.x : 0.0f;
            w.y = (w.y > thrf || (w.y == thrf && r1 < need)) ? w.y : 0.0f;
            w.z = (w.z > thrf || (w.z == thrf && r2 < need)) ? w.z : 0.0f;
            w.w = (w.w > thrf || (w.w == thrf && r3 < need)) ? w.w : 0.0f;
            nt_store4(&ov[lane + 64 * c], w);
            base_c += (unsigned)__popcll(m0) + (unsigned)__popcll(m1)
                    + (unsigned)__popcll(m2) + (unsigned)__popcll(m3);
        }
    }
}

extern "C" void kernel_launch(void* const* d_in, const int* in_sizes, int n_in,
                              void* d_out, int out_size, void* d_ws, size_t ws_size,
                              hipStream_t stream) {
    const float* x = (const float*)d_in[0];
    float* out = (float*)d_out;
    int rows = in_sizes[0] / DIM;             // 16384
    sparsify_topk<<<rows / WPB, 256, 0, stream>>>(x, out);
}